// Round 7
// baseline (563.927 us; speedup 1.0000x reference)
//
#include <hip/hip_runtime.h>
#include <math.h>

#define Lq 1024
#define Hq 8
#define Eq 64
#define LDW 72   // padded row length (bf16 elems); 144 B rows, 16B-aligned

// slot -> source head: _PERM=[6,2,1,7,3,0,5,4]; slots 0..6 = series {2,1,7,3,0,5,4}, slot 7 = cross head 6
#define SRC_HEAD_PACKED 0x64503712u

// workspace layout: [0 .. 16KB) merge counters (int per (b,slot,pair));
// then partials: idx = (((b*8+slot)*16 + qtile)*2 + half), each 64 rows x 68 floats (O[64], m, l, pad)
#define WS_CNT_INTS   4096
#define PROW          68
#define PARTIAL_FLTS  (64 * PROW)

typedef __bf16 bf16_t;
typedef __bf16 bf16x8 __attribute__((ext_vector_type(8)));
typedef short  shortx4 __attribute__((ext_vector_type(4)));
typedef float  floatx4 __attribute__((ext_vector_type(4)));

__device__ __forceinline__ bf16x8 cvt8(const float4 a, const float4 b) {
    bf16x8 r;
    r[0] = (bf16_t)a.x; r[1] = (bf16_t)a.y; r[2] = (bf16_t)a.z; r[3] = (bf16_t)a.w;
    r[4] = (bf16_t)b.x; r[5] = (bf16_t)b.y; r[6] = (bf16_t)b.z; r[7] = (bf16_t)b.w;
    return r;
}

__global__ __launch_bounds__(256, 4)
void attn_split(const float* __restrict__ Q, const float* __restrict__ Ks,
                const float* __restrict__ KTs, const float* __restrict__ Vs,
                const float* __restrict__ VTs, float* __restrict__ out,
                float* __restrict__ ws) {
    const int p    = blockIdx.x & 7;        // pair: tiles pA=p (small), pB=15-p (large)
    const int half = blockIdx.x >> 3;       // key-split: even (0) / odd (1) k-tiles
    const int slot = blockIdx.y;
    const int b    = blockIdx.z;
    const int h    = (SRC_HEAD_PACKED >> (slot * 4)) & 0xF;
    const float* __restrict__ Kp = (slot == 7) ? KTs : Ks;
    const float* __restrict__ Vp = (slot == 7) ? VTs : Vs;
    const int pA = p, pB = 15 - p;

    const int tid  = threadIdx.x;
    const int wv   = tid >> 6;
    const int lane = tid & 63;
    const int ln16 = lane & 15;
    const int quad = lane >> 4;

    __shared__ alignas(16) unsigned short k_lds[2][64][LDW];   // K[key][e]
    __shared__ alignas(16) unsigned short vt_lds[2][64][LDW];  // V^T[d][key]
    __shared__ int s_old;

    // ---- Q fragments (B operand of S^T: [n=qrow=ln16][k=e=quad*8+j]); fold scale*log2e ----
    const float qs = 0.125f * 1.44269504f;
    bf16x8 qfA[2], qfB[2];
    {
        const int rA = pA * 64 + wv * 16 + ln16;
        const int rB = pB * 64 + wv * 16 + ln16;
        const float* qa = Q + (((size_t)b * Lq + rA) * Hq + h) * Eq + quad * 8;
        const float* qb = Q + (((size_t)b * Lq + rB) * Hq + h) * Eq + quad * 8;
        #pragma unroll
        for (int ec = 0; ec < 2; ++ec) {
            float4 f0 = ((const float4*)(qa + ec * 32))[0];
            float4 f1 = ((const float4*)(qa + ec * 32))[1];
            float4 g0 = ((const float4*)(qb + ec * 32))[0];
            float4 g1 = ((const float4*)(qb + ec * 32))[1];
            f0.x*=qs; f0.y*=qs; f0.z*=qs; f0.w*=qs; f1.x*=qs; f1.y*=qs; f1.z*=qs; f1.w*=qs;
            g0.x*=qs; g0.y*=qs; g0.z*=qs; g0.w*=qs; g1.x*=qs; g1.y*=qs; g1.z*=qs; g1.w*=qs;
            qfA[ec] = cvt8(f0, f1);
            qfB[ec] = cvt8(g0, g1);
        }
    }

    // O layout (from 16x16x16 PV): row(quad*4+r)=qrow, col(ln16)=d-within-16
    floatx4 OA[4], OB[4];
    #pragma unroll
    for (int i = 0; i < 4; ++i) { OA[i] = (floatx4){0,0,0,0}; OB[i] = (floatx4){0,0,0,0}; }
    float mA = -INFINITY, lA = 0.f, mB = -INFINITY, lB = 0.f;

    // staging lane assignment, bank-rotated (2-way = free)
    const int kj = tid >> 2;
    const int kc = ((((tid & 3) + kj) & 3)) * 16;
    const int vd = lane;
    const int vk = (((tid >> 6) + (vd >> 4)) & 3) * 16;

    float4 kq[4];
    float  vq[16];
    auto load_tile = [&](int kt) {
        const float* kb = Kp + (((size_t)b * Lq + kt * 64 + kj) * Hq + h) * Eq + kc;
        kq[0] = ((const float4*)kb)[0]; kq[1] = ((const float4*)kb)[1];
        kq[2] = ((const float4*)kb)[2]; kq[3] = ((const float4*)kb)[3];
        const float* vb = Vp + (((size_t)b * Lq + kt * 64 + vk) * Hq + h) * Eq + vd;
        #pragma unroll
        for (int i = 0; i < 16; ++i) vq[i] = vb[(size_t)i * (Hq * Eq)];
    };
    auto stage = [&](int buf) {
        *(bf16x8*)&k_lds[buf][kj][kc]     = cvt8(kq[0], kq[1]);
        *(bf16x8*)&k_lds[buf][kj][kc + 8] = cvt8(kq[2], kq[3]);
        const float4* vq4 = (const float4*)vq;
        *(bf16x8*)&vt_lds[buf][vd][vk]     = cvt8(vq4[0], vq4[1]);
        *(bf16x8*)&vt_lds[buf][vd][vk + 8] = cvt8(vq4[2], vq4[3]);
    };

    auto process = [&](const bf16x8 (&qf)[2], bf16x8 (&kf)[4][2], shortx4 (&vf)[4][4],
                       floatx4 (&O)[4], float& m, float& l, bool diag) {
        // S^T = K Q^T : C-layout col(ln16)=qrow, row(quad*4+r)=key nc*16+quad*4+r
        floatx4 s[4];
        #pragma unroll
        for (int nc = 0; nc < 4; ++nc) {
            floatx4 acc = (floatx4){0,0,0,0};
            acc = __builtin_amdgcn_mfma_f32_16x16x32_bf16(kf[nc][0], qf[0], acc, 0, 0, 0);
            acc = __builtin_amdgcn_mfma_f32_16x16x32_bf16(kf[nc][1], qf[1], acc, 0, 0, 0);
            s[nc] = acc;
        }
        if (diag) {
            const int rin = wv * 16 + ln16;
            #pragma unroll
            for (int nc = 0; nc < 4; ++nc)
                #pragma unroll
                for (int r = 0; r < 4; ++r)
                    if (nc * 16 + quad * 4 + r > rin) s[nc][r] = -INFINITY;
        }
        float mn = s[0][0];
        #pragma unroll
        for (int nc = 0; nc < 4; ++nc)
            #pragma unroll
            for (int r = 0; r < 4; ++r) mn = fmaxf(mn, s[nc][r]);
        mn = fmaxf(mn, __shfl_xor(mn, 16, 64));
        mn = fmaxf(mn, __shfl_xor(mn, 32, 64));
        mn = fmaxf(mn, m);
        const float alpha = __builtin_amdgcn_exp2f(m - mn);
        m = mn;
        float ps = 0.f;
        float pv[4][4];
        #pragma unroll
        for (int nc = 0; nc < 4; ++nc)
            #pragma unroll
            for (int r = 0; r < 4; ++r) { pv[nc][r] = __builtin_amdgcn_exp2f(s[nc][r] - mn); ps += pv[nc][r]; }
        ps += __shfl_xor(ps, 16, 64);
        ps += __shfl_xor(ps, 32, 64);
        l = l * alpha + ps;
        float aO[4];
        #pragma unroll
        for (int r = 0; r < 4; ++r) aO[r] = __shfl(alpha, quad * 4 + r, 64);
        #pragma unroll
        for (int dc = 0; dc < 4; ++dc)
            #pragma unroll
            for (int r = 0; r < 4; ++r) O[dc][r] *= aO[r];
        shortx4 pa[4];
        #pragma unroll
        for (int nc = 0; nc < 4; ++nc) {
            union { shortx4 s4; bf16_t bf[4]; } u;
            u.bf[0] = (bf16_t)pv[nc][0]; u.bf[1] = (bf16_t)pv[nc][1];
            u.bf[2] = (bf16_t)pv[nc][2]; u.bf[3] = (bf16_t)pv[nc][3];
            pa[nc] = u.s4;
        }
        #pragma unroll
        for (int dc = 0; dc < 4; ++dc)
            #pragma unroll
            for (int nc = 0; nc < 4; ++nc)
                O[dc] = __builtin_amdgcn_mfma_f32_16x16x16bf16_1k(pa[nc], vf[dc][nc], O[dc], 0, 0, 0);
    };

    // ---- main loop: this half owns k-tiles {half, half+2, ...} ----
    if (half <= pB) {
        load_tile(half);
        stage(0);
        if (half + 2 <= pB) load_tile(half + 2);
    }
    __syncthreads();
    int it = 0;
    for (int kt = half; kt <= pB; kt += 2, ++it) {
        const int cur = it & 1, nxt = cur ^ 1;
        if (kt + 2 <= pB) stage(nxt);
        if (kt + 4 <= pB) load_tile(kt + 4);
        bf16x8 kf[4][2];
        shortx4 vf[4][4];
        #pragma unroll
        for (int c = 0; c < 4; ++c) {
            kf[c][0] = *(const bf16x8*)&k_lds[cur][c * 16 + ln16][quad * 8];
            kf[c][1] = *(const bf16x8*)&k_lds[cur][c * 16 + ln16][32 + quad * 8];
        }
        #pragma unroll
        for (int dc = 0; dc < 4; ++dc)
            #pragma unroll
            for (int nc = 0; nc < 4; ++nc)
                vf[dc][nc] = *(const shortx4*)&vt_lds[cur][dc * 16 + ln16][nc * 16 + quad * 4];
        if (kt <= pA) process(qfA, kf, vf, OA, mA, lA, kt == pA);
        process(qfB, kf, vf, OB, mB, lB, kt == pB);
        if (kt + 2 <= pB) __syncthreads();
    }

    // ---- write partials (unnormalized O, m, l) ----
    float* pbase = ws + WS_CNT_INTS;
    const int idxA = (((b * 8 + slot) * 16 + pA) * 2 + half);
    const int idxB = (((b * 8 + slot) * 16 + pB) * 2 + half);
    {
        float* pb = pbase + (size_t)idxA * PARTIAL_FLTS;
        #pragma unroll
        for (int dc = 0; dc < 4; ++dc)
            #pragma unroll
            for (int r = 0; r < 4; ++r)
                pb[(wv * 16 + quad * 4 + r) * PROW + dc * 16 + ln16] = OA[dc][r];
        if (quad == 0) { pb[(wv * 16 + ln16) * PROW + 64] = mA; pb[(wv * 16 + ln16) * PROW + 65] = lA; }
    }
    {
        float* pb = pbase + (size_t)idxB * PARTIAL_FLTS;
        #pragma unroll
        for (int dc = 0; dc < 4; ++dc)
            #pragma unroll
            for (int r = 0; r < 4; ++r)
                pb[(wv * 16 + quad * 4 + r) * PROW + dc * 16 + ln16] = OB[dc][r];
        if (quad == 0) { pb[(wv * 16 + ln16) * PROW + 64] = mB; pb[(wv * 16 + ln16) * PROW + 65] = lB; }
    }

    // ---- arrival protocol: second block merges ----
    __threadfence();
    __syncthreads();
    if (tid == 0) s_old = atomicAdd((int*)ws + ((b * 8 + slot) * 8 + p), 1);
    __syncthreads();
    if (s_old == 0) return;      // first arrival: sibling will merge
    __threadfence();             // make sibling's partial writes visible

    auto merge_store = [&](floatx4 (&O)[4], float m, float l, int qt, int sidx) {
        const float* pb = pbase + (size_t)sidx * PARTIAL_FLTS;
        #pragma unroll
        for (int r = 0; r < 4; ++r) {
            const int rin = wv * 16 + quad * 4 + r;
            const float m0 = __shfl(m, quad * 4 + r, 64);
            const float l0 = __shfl(l, quad * 4 + r, 64);
            const float m1 = pb[rin * PROW + 64];
            const float l1 = pb[rin * PROW + 65];
            const float mm = fmaxf(m0, m1);
            const float w0 = __builtin_amdgcn_exp2f(m0 - mm);
            const float w1 = __builtin_amdgcn_exp2f(m1 - mm);
            const float inv = 1.0f / (l0 * w0 + l1 * w1);
            float* op = out + (((size_t)b * Lq + qt * 64 + rin) * Hq + slot) * Eq + ln16;
            #pragma unroll
            for (int dc = 0; dc < 4; ++dc)
                op[dc * 16] = (O[dc][r] * w0 + pb[rin * PROW + dc * 16 + ln16] * w1) * inv;
        }
    };
    const int sh = half ^ 1;
    merge_store(OA, mA, lA, pA, (((b * 8 + slot) * 16 + pA) * 2 + sh));
    merge_store(OB, mB, lB, pB, (((b * 8 + slot) * 16 + pB) * 2 + sh));
}

extern "C" void kernel_launch(void* const* d_in, const int* in_sizes, int n_in,
                              void* d_out, int out_size, void* d_ws, size_t ws_size,
                              hipStream_t stream) {
    const float* queries = (const float*)d_in[0];
    const float* keys    = (const float*)d_in[1];
    const float* keysT   = (const float*)d_in[2];
    const float* values  = (const float*)d_in[3];
    const float* valuesT = (const float*)d_in[4];
    float* out = (float*)d_out;

    // zero the merge counters (first 16 KB of ws) every call — capture-safe
    hipMemsetAsync(d_ws, 0, WS_CNT_INTS * sizeof(int), stream);

    dim3 grid(16, Hq, 8);   // (pair|half, slot, batch) = 1024 blocks
    dim3 block(256);
    attn_split<<<grid, block, 0, stream>>>(queries, keys, keysT, values, valuesT, out,
                                           (float*)d_ws);
}

// Round 8
// 408.223 us; speedup vs baseline: 1.3814x; 1.3814x over previous
//
#include <hip/hip_runtime.h>
#include <math.h>

#define Lq 1024
#define Hq 8
#define Eq 64
#define LDW 72   // padded row length (bf16 elems); 144 B rows, 16B-aligned

// slot -> source head: _PERM=[6,2,1,7,3,0,5,4]; slots 0..6 = series {2,1,7,3,0,5,4}, slot 7 = cross head 6
#define SRC_HEAD_PACKED 0x64503712u

// workspace layout: [0 .. 16KB) merge counters (int per (b,slot,pair));
// then partials: idx = (((b*8+slot)*16 + qtile)*2 + half), each 64 rows x 68 floats (O[64], m, l, pad)
#define WS_CNT_INTS   4096
#define PROW          68
#define PARTIAL_FLTS  (64 * PROW)

typedef __bf16 bf16_t;
typedef __bf16 bf16x8 __attribute__((ext_vector_type(8)));
typedef short  shortx4 __attribute__((ext_vector_type(4)));
typedef float  floatx4 __attribute__((ext_vector_type(4)));

__device__ __forceinline__ bf16x8 cvt8(const float4 a, const float4 b) {
    bf16x8 r;
    r[0] = (bf16_t)a.x; r[1] = (bf16_t)a.y; r[2] = (bf16_t)a.z; r[3] = (bf16_t)a.w;
    r[4] = (bf16_t)b.x; r[5] = (bf16_t)b.y; r[6] = (bf16_t)b.z; r[7] = (bf16_t)b.w;
    return r;
}

// NOTE: second arg 2 (NOT 4): it is only a VGPR-allocator cap. At ~110 VGPR /
// 37.4 KB LDS the HW already fits 4 blocks/CU; capping to 128 VGPRs (arg=4)
// caused catastrophic scratch spill in rounds 5 and 7 (WRITE_SIZE 333-400 MB).
__global__ __launch_bounds__(256, 2)
void attn_split(const float* __restrict__ Q, const float* __restrict__ Ks,
                const float* __restrict__ KTs, const float* __restrict__ Vs,
                const float* __restrict__ VTs, float* __restrict__ out,
                float* __restrict__ ws) {
    const int p    = blockIdx.x & 7;        // pair: tiles pA=p (small), pB=15-p (large)
    const int half = blockIdx.x >> 3;       // key-split: even (0) / odd (1) k-tiles
    const int slot = blockIdx.y;
    const int b    = blockIdx.z;
    const int h    = (SRC_HEAD_PACKED >> (slot * 4)) & 0xF;
    const float* __restrict__ Kp = (slot == 7) ? KTs : Ks;
    const float* __restrict__ Vp = (slot == 7) ? VTs : Vs;
    const int pA = p, pB = 15 - p;

    const int tid  = threadIdx.x;
    const int wv   = tid >> 6;
    const int lane = tid & 63;
    const int ln16 = lane & 15;
    const int quad = lane >> 4;

    __shared__ alignas(16) unsigned short k_lds[2][64][LDW];   // K[key][e]
    __shared__ alignas(16) unsigned short vt_lds[2][64][LDW];  // V^T[d][key]
    __shared__ int s_old;

    // ---- Q fragments (B operand of S^T: [n=qrow=ln16][k=e=quad*8+j]); fold scale*log2e ----
    const float qs = 0.125f * 1.44269504f;
    bf16x8 qfA[2], qfB[2];
    {
        const int rA = pA * 64 + wv * 16 + ln16;
        const int rB = pB * 64 + wv * 16 + ln16;
        const float* qa = Q + (((size_t)b * Lq + rA) * Hq + h) * Eq + quad * 8;
        const float* qb = Q + (((size_t)b * Lq + rB) * Hq + h) * Eq + quad * 8;
        #pragma unroll
        for (int ec = 0; ec < 2; ++ec) {
            float4 f0 = ((const float4*)(qa + ec * 32))[0];
            float4 f1 = ((const float4*)(qa + ec * 32))[1];
            float4 g0 = ((const float4*)(qb + ec * 32))[0];
            float4 g1 = ((const float4*)(qb + ec * 32))[1];
            f0.x*=qs; f0.y*=qs; f0.z*=qs; f0.w*=qs; f1.x*=qs; f1.y*=qs; f1.z*=qs; f1.w*=qs;
            g0.x*=qs; g0.y*=qs; g0.z*=qs; g0.w*=qs; g1.x*=qs; g1.y*=qs; g1.z*=qs; g1.w*=qs;
            qfA[ec] = cvt8(f0, f1);
            qfB[ec] = cvt8(g0, g1);
        }
    }

    // O layout (from 16x16x16 PV): row(quad*4+r)=qrow, col(ln16)=d-within-16
    floatx4 OA[4], OB[4];
    #pragma unroll
    for (int i = 0; i < 4; ++i) { OA[i] = (floatx4){0,0,0,0}; OB[i] = (floatx4){0,0,0,0}; }
    float mA = -INFINITY, lA = 0.f, mB = -INFINITY, lB = 0.f;

    // staging lane assignment, bank-rotated (2-way = free)
    const int kj = tid >> 2;
    const int kc = ((((tid & 3) + kj) & 3)) * 16;
    const int vd = lane;
    const int vk = (((tid >> 6) + (vd >> 4)) & 3) * 16;

    float4 kq[4];
    float  vq[16];
    auto load_tile = [&](int kt) {
        const float* kb = Kp + (((size_t)b * Lq + kt * 64 + kj) * Hq + h) * Eq + kc;
        kq[0] = ((const float4*)kb)[0]; kq[1] = ((const float4*)kb)[1];
        kq[2] = ((const float4*)kb)[2]; kq[3] = ((const float4*)kb)[3];
        const float* vb = Vp + (((size_t)b * Lq + kt * 64 + vk) * Hq + h) * Eq + vd;
        #pragma unroll
        for (int i = 0; i < 16; ++i) vq[i] = vb[(size_t)i * (Hq * Eq)];
    };
    auto stage = [&](int buf) {
        *(bf16x8*)&k_lds[buf][kj][kc]     = cvt8(kq[0], kq[1]);
        *(bf16x8*)&k_lds[buf][kj][kc + 8] = cvt8(kq[2], kq[3]);
        const float4* vq4 = (const float4*)vq;
        *(bf16x8*)&vt_lds[buf][vd][vk]     = cvt8(vq4[0], vq4[1]);
        *(bf16x8*)&vt_lds[buf][vd][vk + 8] = cvt8(vq4[2], vq4[3]);
    };

    auto process = [&](const bf16x8 (&qf)[2], bf16x8 (&kf)[4][2], shortx4 (&vf)[4][4],
                       floatx4 (&O)[4], float& m, float& l, bool diag) {
        // S^T = K Q^T : C-layout col(ln16)=qrow, row(quad*4+r)=key nc*16+quad*4+r
        floatx4 s[4];
        #pragma unroll
        for (int nc = 0; nc < 4; ++nc) {
            floatx4 acc = (floatx4){0,0,0,0};
            acc = __builtin_amdgcn_mfma_f32_16x16x32_bf16(kf[nc][0], qf[0], acc, 0, 0, 0);
            acc = __builtin_amdgcn_mfma_f32_16x16x32_bf16(kf[nc][1], qf[1], acc, 0, 0, 0);
            s[nc] = acc;
        }
        if (diag) {
            const int rin = wv * 16 + ln16;
            #pragma unroll
            for (int nc = 0; nc < 4; ++nc)
                #pragma unroll
                for (int r = 0; r < 4; ++r)
                    if (nc * 16 + quad * 4 + r > rin) s[nc][r] = -INFINITY;
        }
        float mn = s[0][0];
        #pragma unroll
        for (int nc = 0; nc < 4; ++nc)
            #pragma unroll
            for (int r = 0; r < 4; ++r) mn = fmaxf(mn, s[nc][r]);
        mn = fmaxf(mn, __shfl_xor(mn, 16, 64));
        mn = fmaxf(mn, __shfl_xor(mn, 32, 64));
        mn = fmaxf(mn, m);
        const float alpha = __builtin_amdgcn_exp2f(m - mn);
        m = mn;
        float ps = 0.f;
        float pv[4][4];
        #pragma unroll
        for (int nc = 0; nc < 4; ++nc)
            #pragma unroll
            for (int r = 0; r < 4; ++r) { pv[nc][r] = __builtin_amdgcn_exp2f(s[nc][r] - mn); ps += pv[nc][r]; }
        ps += __shfl_xor(ps, 16, 64);
        ps += __shfl_xor(ps, 32, 64);
        l = l * alpha + ps;
        float aO[4];
        #pragma unroll
        for (int r = 0; r < 4; ++r) aO[r] = __shfl(alpha, quad * 4 + r, 64);
        #pragma unroll
        for (int dc = 0; dc < 4; ++dc)
            #pragma unroll
            for (int r = 0; r < 4; ++r) O[dc][r] *= aO[r];
        shortx4 pa[4];
        #pragma unroll
        for (int nc = 0; nc < 4; ++nc) {
            union { shortx4 s4; bf16_t bf[4]; } u;
            u.bf[0] = (bf16_t)pv[nc][0]; u.bf[1] = (bf16_t)pv[nc][1];
            u.bf[2] = (bf16_t)pv[nc][2]; u.bf[3] = (bf16_t)pv[nc][3];
            pa[nc] = u.s4;
        }
        #pragma unroll
        for (int dc = 0; dc < 4; ++dc)
            #pragma unroll
            for (int nc = 0; nc < 4; ++nc)
                O[dc] = __builtin_amdgcn_mfma_f32_16x16x16bf16_1k(pa[nc], vf[dc][nc], O[dc], 0, 0, 0);
    };

    // ---- main loop: this half owns k-tiles {half, half+2, ...} ----
    if (half <= pB) {
        load_tile(half);
        stage(0);
        if (half + 2 <= pB) load_tile(half + 2);
    }
    __syncthreads();
    int it = 0;
    for (int kt = half; kt <= pB; kt += 2, ++it) {
        const int cur = it & 1, nxt = cur ^ 1;
        if (kt + 2 <= pB) stage(nxt);
        if (kt + 4 <= pB) load_tile(kt + 4);
        bf16x8 kf[4][2];
        shortx4 vf[4][4];
        #pragma unroll
        for (int c = 0; c < 4; ++c) {
            kf[c][0] = *(const bf16x8*)&k_lds[cur][c * 16 + ln16][quad * 8];
            kf[c][1] = *(const bf16x8*)&k_lds[cur][c * 16 + ln16][32 + quad * 8];
        }
        #pragma unroll
        for (int dc = 0; dc < 4; ++dc)
            #pragma unroll
            for (int nc = 0; nc < 4; ++nc)
                vf[dc][nc] = *(const shortx4*)&vt_lds[cur][dc * 16 + ln16][nc * 16 + quad * 4];
        if (kt <= pA) process(qfA, kf, vf, OA, mA, lA, kt == pA);
        process(qfB, kf, vf, OB, mB, lB, kt == pB);
        if (kt + 2 <= pB) __syncthreads();
    }

    // ---- write partials (unnormalized O, m, l) ----
    float* pbase = ws + WS_CNT_INTS;
    const int idxA = (((b * 8 + slot) * 16 + pA) * 2 + half);
    const int idxB = (((b * 8 + slot) * 16 + pB) * 2 + half);
    {
        float* pb = pbase + (size_t)idxA * PARTIAL_FLTS;
        #pragma unroll
        for (int dc = 0; dc < 4; ++dc)
            #pragma unroll
            for (int r = 0; r < 4; ++r)
                pb[(wv * 16 + quad * 4 + r) * PROW + dc * 16 + ln16] = OA[dc][r];
        if (quad == 0) { pb[(wv * 16 + ln16) * PROW + 64] = mA; pb[(wv * 16 + ln16) * PROW + 65] = lA; }
    }
    {
        float* pb = pbase + (size_t)idxB * PARTIAL_FLTS;
        #pragma unroll
        for (int dc = 0; dc < 4; ++dc)
            #pragma unroll
            for (int r = 0; r < 4; ++r)
                pb[(wv * 16 + quad * 4 + r) * PROW + dc * 16 + ln16] = OB[dc][r];
        if (quad == 0) { pb[(wv * 16 + ln16) * PROW + 64] = mB; pb[(wv * 16 + ln16) * PROW + 65] = lB; }
    }

    // ---- arrival protocol: second block merges ----
    __threadfence();
    __syncthreads();
    if (tid == 0) s_old = atomicAdd((int*)ws + ((b * 8 + slot) * 8 + p), 1);
    __syncthreads();
    if (s_old == 0) return;      // first arrival: sibling will merge
    __threadfence();             // make sibling's partial writes visible

    auto merge_store = [&](floatx4 (&O)[4], float m, float l, int qt, int sidx) {
        const float* pb = pbase + (size_t)sidx * PARTIAL_FLTS;
        #pragma unroll
        for (int r = 0; r < 4; ++r) {
            const int rin = wv * 16 + quad * 4 + r;
            const float m0 = __shfl(m, quad * 4 + r, 64);
            const float l0 = __shfl(l, quad * 4 + r, 64);
            const float m1 = pb[rin * PROW + 64];
            const float l1 = pb[rin * PROW + 65];
            const float mm = fmaxf(m0, m1);
            const float w0 = __builtin_amdgcn_exp2f(m0 - mm);
            const float w1 = __builtin_amdgcn_exp2f(m1 - mm);
            const float inv = 1.0f / (l0 * w0 + l1 * w1);
            float* op = out + (((size_t)b * Lq + qt * 64 + rin) * Hq + slot) * Eq + ln16;
            #pragma unroll
            for (int dc = 0; dc < 4; ++dc)
                op[dc * 16] = (O[dc][r] * w0 + pb[rin * PROW + dc * 16 + ln16] * w1) * inv;
        }
    };
    const int sh = half ^ 1;
    merge_store(OA, mA, lA, pA, (((b * 8 + slot) * 16 + pA) * 2 + sh));
    merge_store(OB, mB, lB, pB, (((b * 8 + slot) * 16 + pB) * 2 + sh));
}

extern "C" void kernel_launch(void* const* d_in, const int* in_sizes, int n_in,
                              void* d_out, int out_size, void* d_ws, size_t ws_size,
                              hipStream_t stream) {
    const float* queries = (const float*)d_in[0];
    const float* keys    = (const float*)d_in[1];
    const float* keysT   = (const float*)d_in[2];
    const float* values  = (const float*)d_in[3];
    const float* valuesT = (const float*)d_in[4];
    float* out = (float*)d_out;

    // zero the merge counters (first 16 KB of ws) every call — capture-safe
    hipMemsetAsync(d_ws, 0, WS_CNT_INTS * sizeof(int), stream);

    dim3 grid(16, Hq, 8);   // (pair|half, slot, batch) = 1024 blocks
    dim3 block(256);
    attn_split<<<grid, block, 0, stream>>>(queries, keys, keysT, values, valuesT, out,
                                           (float*)d_ws);
}